// Round 3
// baseline (11971.349 us; speedup 1.0000x reference)
//
#include <hip/hip_runtime.h>
#include <hip/hip_cooperative_groups.h>

namespace cg = cooperative_groups;

// RNN_90829968376262 — Round 3.
// Scan = ONE persistent cooperative kernel: 256 blocks (1/CU), W_hh column
// slice [1024][32] fp32 resident in LDS (128 KB) for all 255 steps; per step
// each block computes its 32x32 (batch x hidden) tile full-K, tanh, writes,
// grid.sync(). No partial-sum round-trips, no per-step launches.
// Numerics: recurrence stays pure fp32 (round-1/2 evidence: fp32 noise alone
// is already amplified to absmax 0.0156 of the 0.0769 budget; bf16 in the
// loop would blow it). Phase 3 (direct output) stays bf16 MFMA.

#define T_STEPS 256
#define B_SZ    256
#define V_SZ    512
#define H_SZ    1024
#define BH      (B_SZ * H_SZ)          // 262144
#define M1      (T_STEPS * B_SZ)       // 65536

typedef __attribute__((ext_vector_type(8))) short bf16x8;
typedef __attribute__((ext_vector_type(4))) float f32x4;

__device__ inline unsigned short bf16_rne(float f) {
    unsigned u = __float_as_uint(f);
    u += 0x7fffu + ((u >> 16) & 1u);
    return (unsigned short)(u >> 16);
}

// =====================  Phase 1: fp32 GEMM 128x128 tile =====================
__global__ __launch_bounds__(256, 4)
void gemm_f32_xh(const float* __restrict__ A, const float* __restrict__ Bw,
                 const float* __restrict__ bias, float* __restrict__ C)
{
    __shared__ __align__(16) float As[16][128];
    __shared__ __align__(16) float Bs[16][128];
    const int tid = threadIdx.x;
    const int tx = tid & 15, ty = tid >> 4;
    const int r0 = blockIdx.y * 128, c0 = blockIdx.x * 128;
    const int ar = tid >> 1, ak = (tid & 1) * 8;
    const int bk = tid >> 4, bc = (tid & 15) * 8;

    float acc[8][8] = {};

    for (int kc = 0; kc < V_SZ; kc += 16) {
        const float* ap = A + (size_t)(r0 + ar) * V_SZ + kc + ak;
        float4 a0 = ((const float4*)ap)[0];
        float4 a1 = ((const float4*)ap)[1];
        const float* bp = Bw + (size_t)(kc + bk) * H_SZ + c0 + bc;
        float4 b0 = ((const float4*)bp)[0];
        float4 b1 = ((const float4*)bp)[1];
        __syncthreads();
        As[ak + 0][ar] = a0.x; As[ak + 1][ar] = a0.y;
        As[ak + 2][ar] = a0.z; As[ak + 3][ar] = a0.w;
        As[ak + 4][ar] = a1.x; As[ak + 5][ar] = a1.y;
        As[ak + 6][ar] = a1.z; As[ak + 7][ar] = a1.w;
        *(float4*)&Bs[bk][bc]     = b0;
        *(float4*)&Bs[bk][bc + 4] = b1;
        __syncthreads();
#pragma unroll
        for (int kk = 0; kk < 16; ++kk) {
            float ra[8], rb[8];
            *(float4*)(ra)     = *(const float4*)&As[kk][ty * 8];
            *(float4*)(ra + 4) = *(const float4*)&As[kk][ty * 8 + 4];
            *(float4*)(rb)     = *(const float4*)&Bs[kk][tx * 8];
            *(float4*)(rb + 4) = *(const float4*)&Bs[kk][tx * 8 + 4];
#pragma unroll
            for (int i = 0; i < 8; ++i)
#pragma unroll
                for (int j = 0; j < 8; ++j)
                    acc[i][j] += ra[i] * rb[j];
        }
    }

    float4 bv0 = *(const float4*)(bias + c0 + tx * 8);
    float4 bv1 = *(const float4*)(bias + c0 + tx * 8 + 4);
#pragma unroll
    for (int i = 0; i < 8; ++i) {
        float* cp = C + (size_t)(r0 + ty * 8 + i) * H_SZ + c0 + tx * 8;
        float4 o0, o1;
        o0.x = acc[i][0] + bv0.x; o0.y = acc[i][1] + bv0.y;
        o0.z = acc[i][2] + bv0.z; o0.w = acc[i][3] + bv0.w;
        o1.x = acc[i][4] + bv1.x; o1.y = acc[i][5] + bv1.y;
        o1.z = acc[i][6] + bv1.z; o1.w = acc[i][7] + bv1.w;
        ((float4*)cp)[0] = o0;
        ((float4*)cp)[1] = o1;
    }
}

// =====================  Scan: persistent cooperative kernel =================
// Grid 256 blocks x 256 threads. Block b: rows r0 = (b>>5)*32 (batch),
// cols c0 = (b&31)*32 (hidden). LDS: Ws[1024][32] fp32 (128 KB, resident) +
// wave-private double-buffered h chunks hs[4][2][8][36] (9 KB).
// Wave w owns 8 rows; lane: rl = lane>>3 (row), c4 = lane&7 (col quad);
// micro-tile 1 row x 4 cols, K unrolled by 4 with b128 LDS reads.
__global__ __launch_bounds__(256, 1)
void scan_coop(const float* __restrict__ Whh, float* buf)
{
    __shared__ __align__(16) float Ws[H_SZ][32];
    __shared__ __align__(16) float hs[4][2][8][36];

    const int tid = threadIdx.x;
    const int bid = blockIdx.x;
    const int r0 = (bid >> 5) * 32;
    const int c0 = (bid & 31) * 32;
    const int w = tid >> 6;
    const int lane = tid & 63;
    const int rl = lane >> 3;       // 0..7: row within wave's 8
    const int c4 = lane & 7;        // 0..7: col quad / staging k-quad
    const int wr0 = r0 + w * 8;     // wave's global row base

    cg::grid_group grid = cg::this_grid();

    // Load W_hh column slice into LDS (once, resident for all steps).
    for (int it = 0; it < 32; ++it) {
        int idx = it * 256 + tid;
        int k = idx >> 3, cq = idx & 7;
        *(float4*)&Ws[k][cq * 4] =
            *(const float4*)(Whh + (size_t)k * H_SZ + c0 + cq * 4);
    }
    // t = 0: h0 = 0 -> h_0 = tanh(xh[0]) on this block's tile.
    {
        int r = tid >> 3, cq = tid & 7;
        float* p = buf + (size_t)(r0 + r) * H_SZ + c0 + cq * 4;
        float4 x = *(float4*)p;
        float4 o;
        o.x = tanhf(x.x); o.y = tanhf(x.y); o.z = tanhf(x.z); o.w = tanhf(x.w);
        *(float4*)p = o;
    }
    __syncthreads();
    grid.sync();

    for (int t = 1; t < T_STEPS; ++t) {
        const float* hprev = buf + (size_t)(t - 1) * BH;
        float* hcur = buf + (size_t)t * BH;   // holds xh[t]; overwritten with h_t

        const float* arow = hprev + (size_t)(wr0 + rl) * H_SZ;
        // prefetch xh for the epilogue (hcur untouched until then)
        float4 xh = *(const float4*)(hcur + (size_t)(wr0 + rl) * H_SZ + c0 + c4 * 4);

        float4 acc; acc.x = acc.y = acc.z = acc.w = 0.f;

        // stage chunk 0 (wave-private: each wave stages only its 8 rows)
        float4 pre = *(const float4*)(arow + c4 * 4);
        *(float4*)&hs[w][0][rl][c4 * 4] = pre;

        for (int ch = 0; ch < 32; ++ch) {
            const int cur = ch & 1;
            float4 nxt;
            if (ch < 31)
                nxt = *(const float4*)(arow + (ch + 1) * 32 + c4 * 4);
#pragma unroll
            for (int kq = 0; kq < 8; ++kq) {
                float4 a = *(const float4*)&hs[w][cur][rl][kq * 4];
                const int kb = ch * 32 + kq * 4;
                float4 b0 = *(const float4*)&Ws[kb + 0][c4 * 4];
                float4 b1 = *(const float4*)&Ws[kb + 1][c4 * 4];
                float4 b2 = *(const float4*)&Ws[kb + 2][c4 * 4];
                float4 b3 = *(const float4*)&Ws[kb + 3][c4 * 4];
                acc.x += a.x * b0.x + a.y * b1.x + a.z * b2.x + a.w * b3.x;
                acc.y += a.x * b0.y + a.y * b1.y + a.z * b2.y + a.w * b3.y;
                acc.z += a.x * b0.z + a.y * b1.z + a.z * b2.z + a.w * b3.z;
                acc.w += a.x * b0.w + a.y * b1.w + a.z * b2.w + a.w * b3.w;
            }
            if (ch < 31)
                *(float4*)&hs[w][cur ^ 1][rl][c4 * 4] = nxt;
        }

        float4 o;
        o.x = tanhf(xh.x + acc.x);
        o.y = tanhf(xh.y + acc.y);
        o.z = tanhf(xh.z + acc.z);
        o.w = tanhf(xh.w + acc.w);
        *(float4*)(hcur + (size_t)(wr0 + rl) * H_SZ + c0 + c4 * 4) = o;

        grid.sync();
    }
}

// =====================  W_dense pre-pass: transpose + cvt bf16 ==============
__global__ __launch_bounds__(256)
void cvt_wdense(const float* __restrict__ Wd, unsigned short* __restrict__ WdT)
{
    __shared__ float tile[64][65];
    const int tid = threadIdx.x;
    const int kt = blockIdx.x * 64, nt = blockIdx.y * 64;
    const int kr = tid >> 2, nc = (tid & 3) * 16;
#pragma unroll
    for (int i = 0; i < 4; ++i) {
        float4 v = *(const float4*)(Wd + (size_t)(kt + kr) * V_SZ + nt + nc + i * 4);
        tile[kr][nc + i * 4 + 0] = v.x;
        tile[kr][nc + i * 4 + 1] = v.y;
        tile[kr][nc + i * 4 + 2] = v.z;
        tile[kr][nc + i * 4 + 3] = v.w;
    }
    __syncthreads();
    const int nr = tid >> 2, kc = (tid & 3) * 16;
    unsigned words[8];
#pragma unroll
    for (int j = 0; j < 8; ++j) {
        unsigned short lo = bf16_rne(tile[kc + 2 * j][nr]);
        unsigned short hi = bf16_rne(tile[kc + 2 * j + 1][nr]);
        words[j] = (unsigned)lo | ((unsigned)hi << 16);
    }
    unsigned* wp = (unsigned*)(WdT + (size_t)(nt + nr) * H_SZ + kt + kc);
    ((uint4*)wp)[0] = make_uint4(words[0], words[1], words[2], words[3]);
    ((uint4*)wp)[1] = make_uint4(words[4], words[5], words[6], words[7]);
}

// =====================  Phase 3: bf16 MFMA GEMM 128x128 tile ================
__global__ __launch_bounds__(256, 2)
void gemm_out_mfma(const float* __restrict__ hs, const unsigned short* __restrict__ WdT,
                   const float* __restrict__ bias, float* __restrict__ out)
{
    __shared__ __align__(16) short As[128 * 40];
    __shared__ __align__(16) short Bs[128 * 32];
    const int tid = threadIdx.x;
    const int lane = tid & 63;
    const int w = tid >> 6;
    const int r0 = blockIdx.y * 128, c0 = blockIdx.x * 128;
    const int rw = (w >> 1) * 64, cw = (w & 1) * 64;

    const int s_row = tid & 127;
    const int s_kh  = tid >> 7;
    const int b_n   = tid >> 2;
    const int b_q   = tid & 3;

    f32x4 acc[4][4];
#pragma unroll
    for (int i = 0; i < 4; ++i)
#pragma unroll
        for (int j = 0; j < 4; ++j)
            acc[i][j] = (f32x4){0.f, 0.f, 0.f, 0.f};

    const int l15 = lane & 15, l16 = lane >> 4;

    for (int kc = 0; kc < H_SZ; kc += 32) {
        const float* ap = hs + (size_t)(r0 + s_row) * H_SZ + kc + s_kh * 16;
        float4 a0 = ((const float4*)ap)[0];
        float4 a1 = ((const float4*)ap)[1];
        float4 a2 = ((const float4*)ap)[2];
        float4 a3 = ((const float4*)ap)[3];
        unsigned pk[8];
        pk[0] = __builtin_amdgcn_perm(__float_as_uint(a0.y), __float_as_uint(a0.x), 0x07060302u);
        pk[1] = __builtin_amdgcn_perm(__float_as_uint(a0.w), __float_as_uint(a0.z), 0x07060302u);
        pk[2] = __builtin_amdgcn_perm(__float_as_uint(a1.y), __float_as_uint(a1.x), 0x07060302u);
        pk[3] = __builtin_amdgcn_perm(__float_as_uint(a1.w), __float_as_uint(a1.z), 0x07060302u);
        pk[4] = __builtin_amdgcn_perm(__float_as_uint(a2.y), __float_as_uint(a2.x), 0x07060302u);
        pk[5] = __builtin_amdgcn_perm(__float_as_uint(a2.w), __float_as_uint(a2.z), 0x07060302u);
        pk[6] = __builtin_amdgcn_perm(__float_as_uint(a3.y), __float_as_uint(a3.x), 0x07060302u);
        pk[7] = __builtin_amdgcn_perm(__float_as_uint(a3.w), __float_as_uint(a3.z), 0x07060302u);
        bf16x8 bld0 = *(const bf16x8*)(WdT + (size_t)(c0 + b_n) * H_SZ + kc + b_q * 8);
        bf16x8 bld1 = *(const bf16x8*)(WdT + (size_t)(c0 + b_n + 64) * H_SZ + kc + b_q * 8);
        __syncthreads();
        ((uint4*)&As[s_row * 40 + s_kh * 16])[0] = make_uint4(pk[0], pk[1], pk[2], pk[3]);
        ((uint4*)&As[s_row * 40 + s_kh * 16 + 8])[0] = make_uint4(pk[4], pk[5], pk[6], pk[7]);
        *(bf16x8*)(&Bs[b_n * 32 + b_q * 8]) = bld0;
        *(bf16x8*)(&Bs[(b_n + 64) * 32 + b_q * 8]) = bld1;
        __syncthreads();

        bf16x8 af[4], bfr[4];
#pragma unroll
        for (int mi = 0; mi < 4; ++mi)
            af[mi] = *(const bf16x8*)(&As[(rw + mi * 16 + l15) * 40 + l16 * 8]);
#pragma unroll
        for (int ni = 0; ni < 4; ++ni)
            bfr[ni] = *(const bf16x8*)(&Bs[(cw + ni * 16 + l15) * 32 + l16 * 8]);
#pragma unroll
        for (int mi = 0; mi < 4; ++mi)
#pragma unroll
            for (int ni = 0; ni < 4; ++ni)
                acc[mi][ni] = __builtin_amdgcn_mfma_f32_16x16x32_bf16(
                    af[mi], bfr[ni], acc[mi][ni], 0, 0, 0);
    }

#pragma unroll
    for (int ni = 0; ni < 4; ++ni) {
        const int col = c0 + cw + ni * 16 + l15;
        const float bv = bias[col];
#pragma unroll
        for (int mi = 0; mi < 4; ++mi) {
            const int rowb = r0 + rw + mi * 16 + l16 * 4;
#pragma unroll
            for (int r = 0; r < 4; ++r)
                out[(size_t)(rowb + r) * V_SZ + col] = acc[mi][ni][r] + bv;
        }
    }
}

__global__ __launch_bounds__(256)
void copy_f4(const float* __restrict__ src, float* __restrict__ dst)
{
    int i = blockIdx.x * 256 + threadIdx.x;
    ((float4*)dst)[i] = ((const float4*)src)[i];
}

extern "C" void kernel_launch(void* const* d_in, const int* in_sizes, int n_in,
                              void* d_out, int out_size, void* d_ws, size_t ws_size,
                              hipStream_t stream)
{
    const float* inputs  = (const float*)d_in[0];
    const float* W_xh    = (const float*)d_in[1];
    const float* W_hh    = (const float*)d_in[2];
    const float* b_h     = (const float*)d_in[3];
    const float* W_dense = (const float*)d_in[4];
    const float* b_dense = (const float*)d_in[5];
    float* out = (float*)d_out;

    float* buf = (float*)d_ws;                         // 256 MB: xh -> hs in place
    unsigned short* WdT = (unsigned short*)(out + (size_t)M1 * V_SZ); // 1 MB tail

    // W_dense -> WdT (bf16, transposed) in the out-tail scratch region
    cvt_wdense<<<dim3(H_SZ / 64, V_SZ / 64), 256, 0, stream>>>(W_dense, WdT);

    // Phase 1: xh = inputs @ W_xh + b_h
    gemm_f32_xh<<<dim3(H_SZ / 128, M1 / 128), 256, 0, stream>>>(
        inputs, W_xh, b_h, buf);

    // Phase 2: whole scan in one persistent cooperative kernel
    {
        void* args[] = {(void*)&W_hh, (void*)&buf};
        hipLaunchCooperativeKernel((const void*)scan_coop, dim3(256), dim3(256),
                                   args, 0, stream);
    }

    // Phase 3: outputs = hs @ W_dense + b_dense (bf16 MFMA)
    gemm_out_mfma<<<dim3(V_SZ / 128, M1 / 128), 256, 0, stream>>>(
        buf, WdT, b_dense, out);

    // final state (overwrites the WdT scratch tail)
    copy_f4<<<dim3(BH / 1024), 256, 0, stream>>>(
        buf + (size_t)(T_STEPS - 1) * BH, out + (size_t)M1 * V_SZ);
}